// Round 10
// baseline (154.843 us; speedup 1.0000x reference)
//
#include <hip/hip_runtime.h>
#include <hip/hip_fp16.h>

#define NTOT   6422528   // 16*56*56*128
#define NPERB  401408    // 56*56*128
#define HH     56
#define WW     56
#define CC     128
#define RS     7296      // guarded SAT row stride: 57*128
#define SB     415872    // guarded SAT per-sample: 57*57*128
#define LOG2E  1.4426950408889634f

__device__ __forceinline__ float sigmoidf_fast(float x) {
    return __builtin_amdgcn_rcpf(1.f + __expf(-x));
}

__device__ __forceinline__ void kappa_consts(const float* kap, float* dcs) {
    float v[5]; float mean = 0.f;
    for (int s = 0; s < 5; s++) {
        float lr = 0.6931471805599453f * (float)(s + 1);
        float k_ = 1.f / (1.f + expf(-kap[s]));
        float lk = 1.f / (1.f + expf(-logf(k_ + 1e-7f)));
        v[s] = lk + lr; mean += v[s];
    }
    mean *= 0.2f; float nd = 0.f;
    for (int s = 0; s < 5; s++) { float d = v[s] - mean; dcs[s] = d; nd += d * d; }
    dcs[5] = sqrtf(nd);
}

// ---------- K1: segmented column prefix (depth 28) + fused min/max ----------
__global__ void k_colsum(const float* __restrict__ x, float* __restrict__ S,
                         float* __restrict__ pmn, float* __restrict__ pmx) {
    int p = blockIdx.x;
    int b = p / 56, j = p % 56;
    int c = threadIdx.x & 127, seg = threadIdx.x >> 7;
    int xbase = b * NPERB + j * 128 + c;
    int scol  = b * SB + (j + 1) * 128 + c;
    __shared__ float tot[128];
    __shared__ float rmn[256], rmx[256];
    float mn = 3.4e38f, mx = -3.4e38f;
    float v[28];
    if (seg == 0) {
        S[scol] = 0.f;                          // guard row i=0
        if (j == 0) S[b * SB + c] = 0.f;        // guard corner (0,0)
        float acc = 0.f;
#pragma unroll
        for (int k = 0; k < 28; k++) {
            float xv = x[xbase + k * 7168];
            mn = fminf(mn, xv); mx = fmaxf(mx, xv);
            acc += xv;
            S[scol + (k + 1) * RS] = acc;
        }
        tot[c] = acc;
    } else {
        float acc = 0.f;
#pragma unroll
        for (int k = 0; k < 28; k++) {
            float xv = x[xbase + (28 + k) * 7168];
            mn = fminf(mn, xv); mx = fmaxf(mx, xv);
            acc += xv;
            v[k] = acc;
        }
    }
    __syncthreads();
    if (seg == 1) {
        float base = tot[c];
#pragma unroll
        for (int k = 0; k < 28; k++) S[scol + (29 + k) * RS] = base + v[k];
    }
    rmn[threadIdx.x] = mn; rmx[threadIdx.x] = mx;
    __syncthreads();
    for (int s = 128; s > 0; s >>= 1) {
        if (threadIdx.x < s) {
            rmn[threadIdx.x] = fminf(rmn[threadIdx.x], rmn[threadIdx.x + s]);
            rmx[threadIdx.x] = fmaxf(rmx[threadIdx.x], rmx[threadIdx.x + s]);
        }
        __syncthreads();
    }
    if (threadIdx.x == 0) { pmn[p] = rmn[0]; pmx[p] = rmx[0]; }
}

// ---------- K2: segmented row prefix in place (897th block = prep) ----------
__global__ void k_rowsum(float* __restrict__ S, const float* __restrict__ kap,
                         const float* __restrict__ pmn, const float* __restrict__ pmx,
                         float* __restrict__ xmn, float* __restrict__ xiv,
                         float* __restrict__ dcs, float* __restrict__ sq) {
    int p = blockIdx.x;
    if (p == 896) {                             // prep block
        int t = threadIdx.x;
        for (int k = t; k < 2048; k += 256) sq[k] = 0.f;
        if (t < 16) {
            float mn = 3.4e38f, mx = -3.4e38f;
            for (int k = 0; k < 56; k++) {
                mn = fminf(mn, pmn[t * 56 + k]);
                mx = fmaxf(mx, pmx[t * 56 + k]);
            }
            xmn[t] = mn;
            xiv[t] = 1.f / (mx - mn + 1e-7f);
        } else if (t == 32) kappa_consts(kap, dcs);
        return;
    }
    int b = p / 56, i = (p % 56) + 1;
    int c = threadIdx.x & 127, seg = threadIdx.x >> 7;
    int rowbase = b * SB + i * RS + c;
    __shared__ float tot[128];
    float v[28];
    if (seg == 0) {
        S[rowbase] = 0.f;                       // guard col j=0
        float acc = 0.f;
#pragma unroll
        for (int k = 0; k < 28; k++) {
            acc += S[rowbase + (k + 1) * 128];
            S[rowbase + (k + 1) * 128] = acc;
        }
        tot[c] = acc;
    } else {
        float acc = 0.f;
#pragma unroll
        for (int k = 0; k < 28; k++) {
            acc += S[rowbase + (29 + k) * 128];
            v[k] = acc;
        }
    }
    __syncthreads();
    if (seg == 1) {
        float base = tot[c];
#pragma unroll
        for (int k = 0; k < 28; k++) S[rowbase + (29 + k) * 128] = base + v[k];
    }
}

// ---------- K3: gather with wave-uniform fast/slow clamp paths ----------
struct SU {
    const float* ph;   // sp + y1g*RS
    const float* pl;   // sp + y0g*RS
    int chi, clo;      // fast column offsets (already <<7)
    float msub_f;      // fast: -(xm*rows*2hk)*xi
    float xmr_xi;      // slow: xm*rows*xi
    int hk, fast;
};

__global__ void k_gather(const float* __restrict__ S, const float* __restrict__ x,
                         const float* __restrict__ gam, const float* __restrict__ bet,
                         const float* __restrict__ bnm, const float* __restrict__ bnv,
                         const float* __restrict__ xmn, const float* __restrict__ xiv,
                         const float* __restrict__ dcs, float* __restrict__ sq,
                         unsigned int* __restrict__ ABu) {
    int p_ = blockIdx.x;                        // 3584 blocks, XCD slab swizzle
    int L  = (p_ & 7) * 448 + (p_ >> 3);
    int b = L / 224, rem = L % 224;
    int i = rem >> 2, q = rem & 3;
    int c = threadIdx.x & 127, half = threadIdx.x >> 7;
    const float* sp = S + b * SB + c;
    float g = gam[c], be = bet[c], bm = bnm[c];
    float rs = rsqrtf(bnv[c] + 1e-3f);
    float xm = xmn[b], xi = xiv[b];
    float xmxi = xm * xi;
    float A1 = g * rs, A0 = be - g * bm * rs;
    float C1 = -A1 * (LOG2E * 0.1f);
    float C0 = -A0 * LOG2E;
    float d0 = dcs[0], d1 = dcs[1], d2 = dcs[2], d3 = dcs[3], d4 = dcs[4], nd = dcs[5];
    int j0 = q * 14 + half * 7;                 // uniform across each wave

    auto mkU = [&](int hk) {
        SU u; u.hk = hk;
        int y1g = min(i + hk, HH - 1) + 1;
        int y0g = max(i - hk + 1, 0);
        u.ph = sp + y1g * RS;
        u.pl = sp + y0g * RS;
        float rows = (float)(y1g - y0g);
        u.xmr_xi = xm * rows * xi;
        u.msub_f = -u.xmr_xi * (float)(2 * hk);
        u.chi = (hk + 1) << 7;
        u.clo = (1 - hk) << 7;
        u.fast = (j0 >= hk - 1) && (j0 + 6 + hk <= HH - 1);
        return u;
    };
    SU u0 = mkU(1), u1 = mkU(2), u2 = mkU(4), u3 = mkU(8), u4 = mkU(16);

    auto meas = [&](const SU& u, int jof, int j) -> float {
        int o1, o0; float msub;
        if (u.fast) {                           // wave-uniform branch
            o1 = jof + u.chi; o0 = jof + u.clo; msub = u.msub_f;
        } else {
            int x1g = min(j + u.hk, WW - 1) + 1;
            int x0g = max(j - u.hk + 1, 0);
            o1 = x1g << 7; o0 = x0g << 7;
            msub = -u.xmr_xi * (float)(x1g - x0g);
        }
        float s = u.ph[o1] - u.pl[o1] - u.ph[o0] + u.pl[o0];
        return __log2f(fmaxf(fmaf(s, xi, msub), 0.f) + 1e-7f);
    };

    float asum = 0.f;
    int ibase = b * NPERB + i * 7168 + c;
    int jof = j0 << 7;
    for (int jj = 0; jj < 7; jj++, jof += 128) {
        int j = j0 + jj;
        float l0 = meas(u0, jof, j);
        float l1 = meas(u1, jof, j);
        float l2 = meas(u2, jof, j);
        float l3 = meas(u3, jof, j);
        float l4 = meas(u4, jof, j);
        float w2 = -2.f * l0 - l1 + l3 + 2.f * l4;
        asum += w2;
        float alphas = w2 * 0.1f;
        float mean = 0.2f * (l0 + l1 + l2 + l3 + l4);
        float a0 = l0 - mean, a1 = l1 - mean, a2 = l2 - mean, a3 = l3 - mean, a4 = l4 - mean;
        float na2  = a0 * a0 + a1 * a1 + a2 * a2 + a3 * a3 + a4 * a4;
        float adot = a0 * d0 + a1 * d1 + a2 * d2 + a3 * d3 + a4 * d4;
        float na = __builtin_amdgcn_sqrtf(na2);
        float cosv = (alphas * adot) * __builtin_amdgcn_rcpf(na * fabsf(alphas) * nd + 1e-7f);
        float sim = 0.5f * (cosv + 1.f);
        float sbn = __builtin_amdgcn_rcpf(1.f + exp2f(C1 * w2 + C0));
        float xs = fmaf(x[ibase + jof], xi, -xmxi);
        float A = sim * sbn;
        float B = (1.f - sim) * xs;
        __half2 h2 = __floats2half2_rn(A, B);
        ABu[ibase + jof] = __builtin_bit_cast(unsigned int, h2);
    }
    asum *= 0.1f;
    __shared__ float red[256];
    red[threadIdx.x] = asum;
    __syncthreads();
    if (threadIdx.x < 128)
        atomicAdd(&sq[b * 128 + threadIdx.x], red[threadIdx.x] + red[threadIdx.x + 128]);
}

// ---------- K4: fused SE + mix (grid-strided, SE redundant per block) ----------
__launch_bounds__(256)
__global__ void k_mix(const unsigned int* __restrict__ ABu, const float* __restrict__ sq,
                      const float* __restrict__ W1, const float* __restrict__ b1,
                      const float* __restrict__ W2, const float* __restrict__ b2,
                      float* __restrict__ out) {
    __shared__ float buf[2048];
    __shared__ float hid[256];
    int tid = threadIdx.x;
    for (int k = tid; k < 2048; k += 256) buf[k] = sq[k] * (1.f / 3136.f);
    __syncthreads();
    {
        int bb = tid >> 4, h = tid & 15;
        float acc = b1[h];
        for (int c2 = 0; c2 < 128; c2++) acc += buf[bb * 128 + c2] * W1[c2 * 16 + h];
        hid[bb * 16 + h] = fmaxf(acc, 0.f);
    }
    __syncthreads();
    for (int k = tid; k < 2048; k += 256) {
        int bb = k >> 7, c2 = k & 127;
        float acc = b2[c2];
#pragma unroll
        for (int h = 0; h < 16; h++) acc += hid[bb * 16 + h] * W2[h * 128 + c2];
        buf[k] = sigmoidf_fast(acc);
    }
    __syncthreads();
    for (int t = blockIdx.x * 256 + tid; t < NTOT / 4; t += 1024 * 256) {
        int flat = t * 4;
        int b = flat / NPERB, cb = flat & 127;
        uint4 u = ((const uint4*)ABu)[t];
        float2 p0 = __half22float2(__builtin_bit_cast(__half2, u.x));
        float2 p1 = __half22float2(__builtin_bit_cast(__half2, u.y));
        float2 p2 = __half22float2(__builtin_bit_cast(__half2, u.z));
        float2 p3 = __half22float2(__builtin_bit_cast(__half2, u.w));
        ((float4*)out)[t] = make_float4(p0.x + p0.y * buf[b * 128 + cb],
                                        p1.x + p1.y * buf[b * 128 + cb + 1],
                                        p2.x + p2.y * buf[b * 128 + cb + 2],
                                        p3.x + p3.y * buf[b * 128 + cb + 3]);
    }
}

extern "C" void kernel_launch(void* const* d_in, const int* in_sizes, int n_in,
                              void* d_out, int out_size, void* d_ws, size_t ws_size,
                              hipStream_t stream) {
    const float* x   = (const float*)d_in[0];
    const float* kap = (const float*)d_in[1];
    const float* W1  = (const float*)d_in[2];
    const float* b1  = (const float*)d_in[3];
    const float* W2  = (const float*)d_in[4];
    const float* b2  = (const float*)d_in[5];
    const float* gam = (const float*)d_in[6];
    const float* bet = (const float*)d_in[7];
    const float* bnm = (const float*)d_in[8];
    const float* bnv = (const float*)d_in[9];
    float* out = (float*)d_out;

    float*        S   = (float*)d_ws;                   // 16*SB guarded SAT
    unsigned int* ABu = (unsigned int*)(S + 16 * SB);   // NTOT u32 (half2 A,B)
    float* sq  = (float*)(ABu + NTOT);                  // 2048
    float* pmn = sq + 2048;                             // 896 -> 1024
    float* pmx = pmn + 1024;                            // 1024
    float* xmn = pmx + 1024;                            // 16
    float* xiv = xmn + 16;                              // 16
    float* dcs = xiv + 16;                              // 8

    k_colsum<<<896, 256, 0, stream>>>(x, S, pmn, pmx);
    k_rowsum<<<897, 256, 0, stream>>>(S, kap, pmn, pmx, xmn, xiv, dcs, sq);
    k_gather<<<3584, 256, 0, stream>>>(S, x, gam, bet, bnm, bnv, xmn, xiv, dcs, sq, ABu);
    k_mix<<<1024, 256, 0, stream>>>(ABu, sq, W1, b1, W2, b2, out);
}